// Round 1
// baseline (766.665 us; speedup 1.0000x reference)
//
#include <hip/hip_runtime.h>

// Sparsity_Checker: fused passthrough-copy + collector histogram + finalize.
// All four reference outputs derive from the 5-bin histogram of
// collector = sum_t spikes[t] (values 0..T):
//   unique_counts[k]  = hist[k]
//   coll_zero_frac    = hist[0] / total
//   sparsity_ratio    = (total*T - sum_k k*hist[k]) / (total*T)
// Single read of input + single write of output = 411 MB floor (memory-bound).
//
// R1 changes vs 349.5us baseline:
//  - grid 1024 -> 2048 (8 blocks/CU = 32 waves/CU max occupancy: more
//    in-flight requests to absorb HBM read/write turnaround)
//  - nontemporal loads/stores (no reuse: poison fills thrash L3 anyway;
//    avoid L2 write-allocate churn on the 205 MB output stream)
//  - finalize folded into last block (one fewer graph dispatch)

constexpr int T_STEPS = 4;

typedef float f4 __attribute__((ext_vector_type(4)));

__global__ __launch_bounds__(256) void spike_stats_kernel(
    const f4* __restrict__ in, f4* __restrict__ out,
    unsigned int* __restrict__ ws, float* __restrict__ tail,
    int nvec, double total)
{
    unsigned int* hist = ws;        // [5] bins
    unsigned int* done = ws + 5;    // completion counter

    __shared__ unsigned int lhist[5];
    __shared__ bool amLast;
    if (threadIdx.x < 5) lhist[threadIdx.x] = 0u;
    if (threadIdx.x == 0) amLast = false;
    __syncthreads();

    const f4* __restrict__ i0 = in;
    const f4* __restrict__ i1 = in + (size_t)nvec;
    const f4* __restrict__ i2 = in + 2 * (size_t)nvec;
    const f4* __restrict__ i3 = in + 3 * (size_t)nvec;
    f4* __restrict__ o0 = out;
    f4* __restrict__ o1 = out + (size_t)nvec;
    f4* __restrict__ o2 = out + 2 * (size_t)nvec;
    f4* __restrict__ o3 = out + 3 * (size_t)nvec;

    // packed histogram: 5 bins x 12 bits. Per-wave bin max at grid=2048x256:
    // 64 lanes * 4 elems * ceil(3211264/524288)=7 iters = 1792 < 4096.
    unsigned long long packed = 0ull;

    const int stride = gridDim.x * blockDim.x;
    for (int v = blockIdx.x * blockDim.x + threadIdx.x; v < nvec; v += stride) {
        f4 a0 = __builtin_nontemporal_load(i0 + v);
        f4 a1 = __builtin_nontemporal_load(i1 + v);
        f4 a2 = __builtin_nontemporal_load(i2 + v);
        f4 a3 = __builtin_nontemporal_load(i3 + v);
        __builtin_nontemporal_store(a0, o0 + v);
        __builtin_nontemporal_store(a1, o1 + v);
        __builtin_nontemporal_store(a2, o2 + v);
        __builtin_nontemporal_store(a3, o3 + v);
        // elements are exactly 0.0f or 1.0f -> sums are exact small ints
        f4 s = a0 + a1 + a2 + a3;
        int cx = (int)s[0];
        int cy = (int)s[1];
        int cz = (int)s[2];
        int cw = (int)s[3];
        packed += (1ull << (cx * 12)) + (1ull << (cy * 12))
                + (1ull << (cz * 12)) + (1ull << (cw * 12));
    }

    // wave-64 butterfly reduce of the packed histogram
#pragma unroll
    for (int off = 32; off > 0; off >>= 1)
        packed += __shfl_down(packed, off, 64);

    if ((threadIdx.x & 63) == 0) {
#pragma unroll
        for (int k = 0; k < 5; ++k)
            atomicAdd(&lhist[k], (unsigned int)((packed >> (12 * k)) & 0xFFFull));
    }
    __syncthreads();

    // 5 global atomics per block (2048 blocks) — negligible contention.
    // NOTE: all 5 come from wave 0, so the wave-level vmcnt drain implied by
    // the __threadfence below covers them before the done-counter bump.
    if (threadIdx.x < 5)
        atomicAdd(&hist[threadIdx.x], lhist[threadIdx.x]);

    __threadfence();
    if (threadIdx.x == 0) {
        unsigned int prev = __hip_atomic_fetch_add(
            done, 1u, __ATOMIC_ACQ_REL, __HIP_MEMORY_SCOPE_AGENT);
        amLast = (prev == gridDim.x - 1);
    }
    __syncthreads();

    // last block finalizes the scalar tail (replaces separate finalize kernel)
    if (amLast && threadIdx.x == 0) {
        unsigned int h[5];
        double spikes_sum = 0.0;
#pragma unroll
        for (int k = 0; k < 5; ++k) {
            h[k] = __hip_atomic_load(&hist[k], __ATOMIC_RELAXED,
                                     __HIP_MEMORY_SCOPE_AGENT);
            spikes_sum += (double)k * (double)h[k];
        }
        double denom = total * (double)T_STEPS;
        tail[0] = (float)((denom - spikes_sum) / denom); // sparsity_ratio
        tail[1] = (float)((double)h[0] / total);         // coll_zero_frac
#pragma unroll
        for (int k = 0; k < 5; ++k)
            tail[2 + k] = (float)h[k];                   // unique_counts (< 2^24, exact)
    }
}

extern "C" void kernel_launch(void* const* d_in, const int* in_sizes, int n_in,
                              void* d_out, int out_size, void* d_ws, size_t ws_size,
                              hipStream_t stream)
{
    const float* spikes = (const float*)d_in[0];
    float* out = (float*)d_out;

    const long n = (long)in_sizes[0];       // T*B*C*H*W = 51,380,224
    const long per_t = n / T_STEPS;         // 12,845,056 elements per timestep
    const int nvec = (int)(per_t / 4);      // 3,211,264 float4 per timestep

    unsigned int* ws = (unsigned int*)d_ws; // hist[5] + done counter
    hipMemsetAsync(d_ws, 0, 6 * sizeof(unsigned int), stream);

    spike_stats_kernel<<<dim3(2048), dim3(256), 0, stream>>>(
        (const f4*)spikes, (f4*)out, ws, out + n, nvec, (double)per_t);
}